// Round 5
// baseline (543.921 us; speedup 1.0000x reference)
//
#include <hip/hip_runtime.h>
#include <hip/hip_bf16.h>

#define BATCH 16
#define SEQ   2048
#define DIM   128
#define SCALE 0.08838834764831845f  // 1/sqrt(128)

typedef __attribute__((ext_vector_type(8))) short short8;
typedef __attribute__((ext_vector_type(4))) float f32x4;

__device__ __forceinline__ unsigned short f2bf(float x) {
    unsigned int u = __float_as_uint(x);
    u += 0x7fffu + ((u >> 16) & 1u);   // round-to-nearest-even
    return (unsigned short)(u >> 16);
}
__device__ __forceinline__ float bf2f(unsigned short h) {
    return __uint_as_float(((unsigned int)h) << 16);
}
__device__ __forceinline__ void cvt_hl(float x, unsigned short& h, unsigned short& l) {
    h = f2bf(x);
    l = f2bf(x - bf2f(h));             // residual: together ~17 mantissa bits
}

// ---------------------------------------------------------------------------
// Prep: one-time fp32 -> (bf16 hi, bf16 lo) conversion into MFMA-fragment-major
// layouts. Q/K: [b][rt(128)][kc(4)][hl(2)][lane(64)][e(8)]  (A/B over K rows).
// V (transposed for PV B-operand): [b][kc(64)][dt(8)][hl(2)][lane(64)][e(8)].
// ---------------------------------------------------------------------------
__global__ __launch_bounds__(256) void prep_kernel(
    const float* __restrict__ Q, const float* __restrict__ Km, const float* __restrict__ V,
    unsigned short* __restrict__ Qf, unsigned short* __restrict__ Kf,
    unsigned short* __restrict__ Vf)
{
    const int bid = blockIdx.x, t = threadIdx.x;
    if (bid < 4096) {
        const float* src = (bid < 2048) ? Q : Km;
        unsigned short* dst = (bid < 2048) ? Qf : Kf;
        int gid  = (bid & 2047) * 256 + t;      // [0, 524288)
        int lane = gid & 63;
        int kc   = (gid >> 6) & 3;
        int rt   = (gid >> 8) & 127;
        int b    = gid >> 15;
        int row  = rt * 16 + (lane & 15);
        int col  = kc * 32 + (lane >> 4) * 8;
        const float* p = src + ((size_t)b * SEQ + row) * DIM + col;
        float4 f0 = *(const float4*)p;
        float4 f1 = *(const float4*)(p + 4);
        float f[8] = {f0.x, f0.y, f0.z, f0.w, f1.x, f1.y, f1.z, f1.w};
        short8 H, L;
#pragma unroll
        for (int e = 0; e < 8; ++e) {
            unsigned short h, l;
            cvt_hl(f[e], h, l);
            H[e] = (short)h; L[e] = (short)l;
        }
        size_t o = ((size_t)((b * 128 + rt) * 4 + kc) * 2) * 512 + lane * 8;
        *(short8*)&dst[o]       = H;   // hi plane
        *(short8*)&dst[o + 512] = L;   // lo plane
    } else {
        int gid  = (bid - 4096) * 256 + t;      // [0, 524288)
        int lane = gid & 63;
        int dt   = (gid >> 6) & 7;
        int kc   = (gid >> 9) & 63;
        int b    = gid >> 15;
        int d    = dt * 16 + (lane & 15);
        int k0   = kc * 32 + (lane >> 4) * 8;
        const float* p = V + ((size_t)b * SEQ + k0) * DIM + d;
        short8 H, L;
#pragma unroll
        for (int e = 0; e < 8; ++e) {
            float x = p[(size_t)e * DIM];
            unsigned short h, l;
            cvt_hl(x, h, l);
            H[e] = (short)h; L[e] = (short)l;
        }
        size_t o = ((size_t)((b * 64 + kc) * 8 + dt) * 2) * 512 + lane * 8;
        *(short8*)&Vf[o]       = H;
        *(short8*)&Vf[o + 512] = L;
    }
}

// ---------------------------------------------------------------------------
// Fused single kernel, two passes, NO per-iteration barriers:
//   pass 1: QK^T over this wave's k-half, row sums in REGISTERS (shfl reduce)
//   (one __syncthreads to combine the two k-halves' sums via 256 B of LDS)
//   pass 2: recompute QK^T, p = exp(s)*rl (rl lane-local), store E once
//           (coalesced), transpose p via WAVE-PRIVATE LDS scratch (write ->
//           lgkmcnt -> read, no barrier) into PV A-fragments, accumulate O.
// Block: 256 thr = 4 waves = 2 q-groups (wq) x 2 k-halves (wc); 32 q/block.
// Grid 1024 linear -> (b, qt), XCD swizzle (2 batches per XCD).
// Waves fully independent in both hot loops -> wave drift hides latency.
// Epilogue: wc=1 dumps accO to LDS, one barrier, wc=0 adds halves, stores O.
// ---------------------------------------------------------------------------
__global__ __launch_bounds__(256, 4) void attn_fused_kernel(
    const unsigned short* __restrict__ Qf, const unsigned short* __restrict__ Kf,
    const unsigned short* __restrict__ Vf,
    float* __restrict__ E, float* __restrict__ O)
{
    __shared__ float sT[4][16 * 34];    // per-wave transpose scratch (pitch 34: 2-way max)
    __shared__ float sRS[2][2][16];     // [wc][wq][q] row-sum halves
    __shared__ float sO[2][16 * 130];   // [wq][q][d] accO reduce (pitch 130: 2-way max)

    const int Lb = blockIdx.x;
    const int w  = (Lb & 7) * 128 + (Lb >> 3);   // 128 blocks (2 batches) per XCD
    const int b  = w >> 6, qt = w & 63;          // 64 q-tiles of 32 rows
    const int t = threadIdx.x;
    const int lane = t & 63, wave = t >> 6;
    const int quad = lane >> 4, l15 = lane & 15;
    const int wq = wave >> 1, wc = wave & 1;     // wq: q 16-row group; wc: k-half

    // Q fragments register-resident: rt = qt*2 + wq
    short8 qh[4], ql[4];
    const unsigned short* Qb = Qf + (size_t)(b * 128 + qt * 2 + wq) * 4096 + lane * 8;
#pragma unroll
    for (int kc = 0; kc < 4; ++kc) {
        qh[kc] = *(const short8*)(Qb + kc * 1024);
        ql[kc] = *(const short8*)(Qb + kc * 1024 + 512);
    }

    // K base for this wave's k-half (rt offset wc*64)
    const unsigned short* Kb = Kf + (size_t)(b * 128 + wc * 64) * 4096 + lane * 8;

    // ---- pass 1: row sums over k-half, in registers ----
    float rs[4] = {0.f, 0.f, 0.f, 0.f};
#pragma unroll 1
    for (int kt = 0; kt < 32; ++kt) {
        f32x4 accP[2];
        accP[0] = (f32x4){0.f, 0.f, 0.f, 0.f};
        accP[1] = (f32x4){0.f, 0.f, 0.f, 0.f};
#pragma unroll
        for (int kc = 0; kc < 4; ++kc)
#pragma unroll
            for (int j = 0; j < 2; ++j) {
                const unsigned short* pk = Kb + (size_t)(kt * 2 + j) * 4096 + kc * 1024;
                short8 kh = *(const short8*)pk;
                short8 kl = *(const short8*)(pk + 512);
                accP[j] = __builtin_amdgcn_mfma_f32_16x16x32_bf16(qh[kc], kh, accP[j], 0, 0, 0);
                accP[j] = __builtin_amdgcn_mfma_f32_16x16x32_bf16(qh[kc], kl, accP[j], 0, 0, 0);
                accP[j] = __builtin_amdgcn_mfma_f32_16x16x32_bf16(ql[kc], kh, accP[j], 0, 0, 0);
            }
#pragma unroll
        for (int j = 0; j < 2; ++j)
#pragma unroll
            for (int r = 0; r < 4; ++r)
                rs[r] += __expf(accP[j][r] * SCALE);
    }
#pragma unroll
    for (int r = 0; r < 4; ++r) {
        rs[r] += __shfl_xor(rs[r], 1); rs[r] += __shfl_xor(rs[r], 2);
        rs[r] += __shfl_xor(rs[r], 4); rs[r] += __shfl_xor(rs[r], 8);
    }
    if (l15 == 0) {
#pragma unroll
        for (int r = 0; r < 4; ++r)
            sRS[wc][wq][quad * 4 + r] = rs[r];
    }
    __syncthreads();
    float rl[4];
#pragma unroll
    for (int r = 0; r < 4; ++r)
        rl[r] = 1.0f / (sRS[0][wq][quad * 4 + r] + sRS[1][wq][quad * 4 + r]);

    // ---- pass 2: recompute, normalize, write E, PV ----
    f32x4 accO[8];
#pragma unroll
    for (int dt = 0; dt < 8; ++dt)
        accO[dt] = (f32x4){0.f, 0.f, 0.f, 0.f};

    const unsigned short* Vb = Vf + (size_t)b * 524288 + lane * 8;  // kc stride 8192, dt stride 1024
    float* Erow = E + ((size_t)b * SEQ + qt * 32 + wq * 16 + quad * 4) * SEQ + wc * 1024 + l15;
    float* sTw = sT[wave];

#pragma unroll 1
    for (int kt = 0; kt < 32; ++kt) {
        f32x4 accP[2];
        accP[0] = (f32x4){0.f, 0.f, 0.f, 0.f};
        accP[1] = (f32x4){0.f, 0.f, 0.f, 0.f};
#pragma unroll
        for (int kc = 0; kc < 4; ++kc)
#pragma unroll
            for (int j = 0; j < 2; ++j) {
                const unsigned short* pk = Kb + (size_t)(kt * 2 + j) * 4096 + kc * 1024;
                short8 kh = *(const short8*)pk;
                short8 kl = *(const short8*)(pk + 512);
                accP[j] = __builtin_amdgcn_mfma_f32_16x16x32_bf16(qh[kc], kh, accP[j], 0, 0, 0);
                accP[j] = __builtin_amdgcn_mfma_f32_16x16x32_bf16(qh[kc], kl, accP[j], 0, 0, 0);
                accP[j] = __builtin_amdgcn_mfma_f32_16x16x32_bf16(ql[kc], kh, accP[j], 0, 0, 0);
            }
        float p[2][4];
#pragma unroll
        for (int j = 0; j < 2; ++j)
#pragma unroll
            for (int r = 0; r < 4; ++r)
                p[j][r] = __expf(accP[j][r] * SCALE) * rl[r];
        // E store (final attn weights, written once, never read). Coalesced:
        // 16 l15-lanes write 64B runs per (row, j).
#pragma unroll
        for (int j = 0; j < 2; ++j)
#pragma unroll
            for (int r = 0; r < 4; ++r)
                Erow[(size_t)r * SEQ + kt * 32 + j * 16] = p[j][r];
        // wave-private LDS transpose: P[q][k] f32 -> A-fragment order.
        // writes: bank = (8*quad + 2r + 16j + l15)%32 -> 2-way max (free).
#pragma unroll
        for (int j = 0; j < 2; ++j)
#pragma unroll
            for (int r = 0; r < 4; ++r)
                sTw[(quad * 4 + r) * 34 + j * 16 + l15] = p[j][r];
        // reads (same wave; compiler inserts lgkmcnt, no barrier needed):
        // lane holds A[q=l15][k=quad*8+e], e=0..7
        f32x4 pf0 = *(const f32x4*)&sTw[l15 * 34 + quad * 8];
        f32x4 pf1 = *(const f32x4*)&sTw[l15 * 34 + quad * 8 + 4];
        short8 ah, al;
#pragma unroll
        for (int e = 0; e < 4; ++e) {
            unsigned short h, l;
            cvt_hl(pf0[e], h, l);
            ah[e] = (short)h; al[e] = (short)l;
            cvt_hl(pf1[e], h, l);
            ah[4 + e] = (short)h; al[4 + e] = (short)l;
        }
        // PV: accO[dt] += P(16q x 32k) @ V(32k x 16d), 3-term
        const unsigned short* vp = Vb + (size_t)(wc * 32 + kt) * 8192;
#pragma unroll
        for (int dt = 0; dt < 8; ++dt) {
            const unsigned short* pv = vp + dt * 1024;
            short8 bh = *(const short8*)pv;
            short8 bl = *(const short8*)(pv + 512);
            accO[dt] = __builtin_amdgcn_mfma_f32_16x16x32_bf16(ah, bh, accO[dt], 0, 0, 0);
            accO[dt] = __builtin_amdgcn_mfma_f32_16x16x32_bf16(ah, bl, accO[dt], 0, 0, 0);
            accO[dt] = __builtin_amdgcn_mfma_f32_16x16x32_bf16(al, bh, accO[dt], 0, 0, 0);
        }
    }

    // ---- epilogue: combine k-halves' O partials ----
    if (wc == 1) {
        float* so = sO[wq];
#pragma unroll
        for (int dt = 0; dt < 8; ++dt)
#pragma unroll
            for (int r = 0; r < 4; ++r)
                so[(quad * 4 + r) * 130 + dt * 16 + l15] = accO[dt][r];
    }
    __syncthreads();
    if (wc == 0) {
        const float* so = sO[wq];
        float* Ob = O + ((size_t)b * SEQ + qt * 32 + wq * 16 + quad * 4) * DIM + l15;
#pragma unroll
        for (int dt = 0; dt < 8; ++dt)
#pragma unroll
            for (int r = 0; r < 4; ++r)
                Ob[(size_t)r * DIM + dt * 16] = accO[dt][r] + so[(quad * 4 + r) * 130 + dt * 16 + l15];
    }
}

extern "C" void kernel_launch(void* const* d_in, const int* in_sizes, int n_in,
                              void* d_out, int out_size, void* d_ws, size_t ws_size,
                              hipStream_t stream) {
    const float* Q = (const float*)d_in[0];
    const float* K = (const float*)d_in[1];
    const float* V = (const float*)d_in[2];
    float* out  = (float*)d_out;
    float* attn = out + (size_t)BATCH * SEQ * DIM;   // outputs concatenated: (out, attn_weights)

    // workspace layout: Qf (16MB) | Kf (16MB) | Vf (16MB)
    unsigned short* Qf = (unsigned short*)d_ws;
    unsigned short* Kf = Qf + (size_t)8388608;
    unsigned short* Vf = Kf + (size_t)8388608;

    prep_kernel<<<6144, 256, 0, stream>>>(Q, K, V, Qf, Kf, Vf);
    attn_fused_kernel<<<1024, 256, 0, stream>>>(Qf, Kf, Vf, attn, out);
}